// Round 9
// baseline (143.144 us; speedup 1.0000x reference)
//
#include <hip/hip_runtime.h>
#include <hip/hip_bf16.h>

#define NN   4096
#define FIN  512
#define NH   4
#define DD   64

typedef float f32x4 __attribute__((ext_vector_type(4)));
typedef short s16x8 __attribute__((ext_vector_type(8)));

// manual RNE float->bf16
__device__ __forceinline__ short bfbits(float f) {
  union { float f; unsigned u; } v; v.f = f;
  unsigned r = v.u + 0x7FFFu + ((v.u >> 16) & 1u);
  return (short)(r >> 16);
}

// packed pair float->bf16
__device__ __forceinline__ int pkbf(float a, float b) {
  union { float f; unsigned u; } va, vb;
  va.f = a; vb.f = b;
  unsigned ra = (va.u + 0x7FFFu + ((va.u >> 16) & 1u)) >> 16;
  unsigned rb = (vb.u + 0x7FFFu + ((vb.u >> 16) & 1u)) & 0xFFFF0000u;
  return (int)(ra | rb);
}

__device__ __forceinline__ float hexp2(float x) {
#if __has_builtin(__builtin_amdgcn_exp2f)
  return __builtin_amdgcn_exp2f(x);
#else
  return __builtin_exp2f(x);
#endif
}

// ---------------------------------------------------------------------------
// Fused pre-kernel (unchanged from r7, passed): grid 768 = 512 pack + 256 k1
// interleaved 2:1.
// ---------------------------------------------------------------------------
__global__ __launch_bounds__(512, 4) void gat_pre(
    const int* __restrict__ adj, const float* __restrict__ x,
    const float* __restrict__ W, const float* __restrict__ a,
    unsigned long long* __restrict__ bits, short* __restrict__ V2,
    float* __restrict__ ssrc, float* __restrict__ sdst)
{
  __shared__ __align__(16) char sm[34816];
  short* As = (short*)sm;
  short* Bs = (short*)(sm + 17408);
  float* Cs = (float*)sm;

  const int b = blockIdx.x;
  const int t = threadIdx.x;
  const int w = t >> 6, lane = t & 63;

  const int g3 = b / 3, m3 = b - g3 * 3;
  if (m3 < 2) {
    const int pb = g3 * 2 + m3;
    const int rrow = (pb << 3) | w;
    const int* arow = adj + (size_t)rrow * NN;
    unsigned long long mine = 0;
#pragma unroll 8
    for (int it = 0; it < 64; ++it) {
      int v = arow[it * 64 + lane];
      unsigned long long bl = __ballot(v != 0);
      if (lane == it) mine = bl;
    }
    bits[(size_t)rrow * 64 + lane] = mine;
    return;
  }

  const int b2 = g3;
  const int h  = b2 >> 6;
  const int r  = b2 & 63;
  const int n0 = r * 64;
  const int lm = lane & 15, q = lane >> 4;
  const int rs = w & 3, cs = w >> 2;

  f32x4 acc[2] = {};
  const float* Wh = W + (size_t)h * (FIN * DD);

  for (int kq = 0; kq < 4; ++kq) {
    {
      const int row = t >> 3, fl = (t & 7) * 16;
      const float* xp = x + (size_t)(n0 + row) * FIN + kq * 128 + fl;
      float4 v0 = ((const float4*)xp)[0];
      float4 v1 = ((const float4*)xp)[1];
      float4 v2 = ((const float4*)xp)[2];
      float4 v3 = ((const float4*)xp)[3];
      union { short s[8]; int4 v; } u0, u1;
      u0.s[0]=bfbits(v0.x); u0.s[1]=bfbits(v0.y); u0.s[2]=bfbits(v0.z); u0.s[3]=bfbits(v0.w);
      u0.s[4]=bfbits(v1.x); u0.s[5]=bfbits(v1.y); u0.s[6]=bfbits(v1.z); u0.s[7]=bfbits(v1.w);
      u1.s[0]=bfbits(v2.x); u1.s[1]=bfbits(v2.y); u1.s[2]=bfbits(v2.z); u1.s[3]=bfbits(v2.w);
      u1.s[4]=bfbits(v3.x); u1.s[5]=bfbits(v3.y); u1.s[6]=bfbits(v3.z); u1.s[7]=bfbits(v3.w);
      *(int4*)(As + row * 136 + fl)     = u0.v;
      *(int4*)(As + row * 136 + fl + 8) = u1.v;
    }
    {
      const int fl = t >> 2, dc = (t & 3) * 16;
      const float* wp = Wh + (size_t)(kq * 128 + fl) * DD + dc;
      float4 w0 = ((const float4*)wp)[0];
      float4 w1 = ((const float4*)wp)[1];
      float4 w2 = ((const float4*)wp)[2];
      float4 w3 = ((const float4*)wp)[3];
      Bs[(dc+ 0)*136+fl]=bfbits(w0.x); Bs[(dc+ 1)*136+fl]=bfbits(w0.y);
      Bs[(dc+ 2)*136+fl]=bfbits(w0.z); Bs[(dc+ 3)*136+fl]=bfbits(w0.w);
      Bs[(dc+ 4)*136+fl]=bfbits(w1.x); Bs[(dc+ 5)*136+fl]=bfbits(w1.y);
      Bs[(dc+ 6)*136+fl]=bfbits(w1.z); Bs[(dc+ 7)*136+fl]=bfbits(w1.w);
      Bs[(dc+ 8)*136+fl]=bfbits(w2.x); Bs[(dc+ 9)*136+fl]=bfbits(w2.y);
      Bs[(dc+10)*136+fl]=bfbits(w2.z); Bs[(dc+11)*136+fl]=bfbits(w2.w);
      Bs[(dc+12)*136+fl]=bfbits(w3.x); Bs[(dc+13)*136+fl]=bfbits(w3.y);
      Bs[(dc+14)*136+fl]=bfbits(w3.z); Bs[(dc+15)*136+fl]=bfbits(w3.w);
    }
    __syncthreads();
#pragma unroll
    for (int s = 0; s < 4; ++s) {
      s16x8 af = *(const s16x8*)(As + (rs * 16 + lm) * 136 + s * 32 + q * 8);
#pragma unroll
      for (int c = 0; c < 2; ++c) {
        s16x8 bf = *(const s16x8*)(Bs + (cs * 32 + c * 16 + lm) * 136 + s * 32 + q * 8);
        acc[c] = __builtin_amdgcn_mfma_f32_16x16x32_bf16(af, bf, acc[c], 0, 0, 0);
      }
    }
    __syncthreads();
  }

#pragma unroll
  for (int c = 0; c < 2; ++c)
#pragma unroll
    for (int g = 0; g < 4; ++g)
      Cs[(cs * 32 + c * 16 + lm) * 65 + (rs * 16 + q * 4 + g)] = acc[c][g];
  __syncthreads();

  {
    const int d = t >> 3, nc = (t & 7) * 8;
    union { short s[8]; int4 v; } u;
#pragma unroll
    for (int e = 0; e < 8; ++e) u.s[e] = bfbits(Cs[d * 65 + nc + e]);
    *(int4*)(V2 + ((size_t)(h * 128 + r * 2 + (nc >> 5)) * 64 + d) * 32 + (nc & 31)) = u.v;
  }
  if (t < 128) {
    const int n = t & 63;
    const int isdst = t >> 6;
    const float* av = a + h * 128 + isdst * 64;
    float s = 0.f;
#pragma unroll 8
    for (int d = 0; d < 64; ++d) s = fmaf(Cs[d * 65 + n], av[d], s);
    const float LOG2E = 1.4426950408889634f;
    (isdst ? sdst : ssrc)[h * NN + n0 + n] = s * LOG2E;
  }
}

// ---------------------------------------------------------------------------
// Kernel 2 (partial): grid 1024 = rowtile32(128) x head(4) x jhalf(2) ->
// 4 blocks/CU (32 waves/CU, was 16). 8 waves = 8 j-chunks of 256 (8 iters).
// Register-prefetched V/sdst, bitmask adj. Writes partial numerator + row-sum
// to workspace; gat_fin combines.
// ---------------------------------------------------------------------------
__global__ __launch_bounds__(512, 4) void gat_k2p(
    const unsigned* __restrict__ bits, const short* __restrict__ V2,
    const float* __restrict__ ssrc, const float* __restrict__ sdst,
    float* __restrict__ Pn, float* __restrict__ Pl)
{
  __shared__ float MRG[4][32][68];
  __shared__ float Lm[8][32];

  const int b  = blockIdx.x;
  const int rt = b >> 3;            // 0..127
  const int h  = (b >> 1) & 3;
  const int jh = b & 1;
  const int t  = threadIdx.x;
  const int w  = t >> 6, lane = t & 63;
  const int lm = lane & 15, q = lane >> 4;
  const int jc = w;                 // 256-col chunk within half
  const int ib = rt * 32;
  const int i0 = ib + lm, i1 = i0 + 16;

  const float src0 = ssrc[h * NN + i0] - 1000.0f;
  const float src1 = ssrc[h * NN + i1] - 1000.0f;

  const short one = 0x3F80;
  s16x8 bones = {};
  if (lm == 0) {
    bones[0]=one; bones[1]=one; bones[2]=one; bones[3]=one;
    bones[4]=one; bones[5]=one; bones[6]=one; bones[7]=one;
  }

  f32x4 acc[2][4] = {};
  f32x4 accl[2] = {};

  const int jt0 = jh * 64 + jc * 8;            // first 32-col tile index
  const short*  Vb  = V2 + (size_t)h * 262144 + (size_t)jt0 * 2048
                      + lm * 32 + q * 8;                  // +js*2048 +c*512
  const float*  sdh = sdst + h * NN + jt0 * 32 + q * 8;   // +js*32
  const unsigned* b0 = bits + (size_t)i0 * 128 + jt0;
  const unsigned* b1 = bits + (size_t)i1 * 128 + jt0;

  unsigned Wd0[4], Wd1[4], nWd0[4], nWd1[4];
  *(uint4*)Wd0 = ((const uint4*)b0)[0];
  *(uint4*)Wd1 = ((const uint4*)b1)[0];

  s16x8 bfc[4];
#pragma unroll
  for (int c = 0; c < 4; ++c) bfc[c] = *(const s16x8*)(Vb + c * 512);
  float4 S0 = ((const float4*)sdh)[0];
  float4 S1 = ((const float4*)(sdh + 4))[0];

  const int shq = q * 8;

  for (int s = 0; s < 2; ++s) {
    if (s < 1) {
      *(uint4*)nWd0 = ((const uint4*)b0)[1];
      *(uint4*)nWd1 = ((const uint4*)b1)[1];
    }
#pragma unroll
    for (int jsub = 0; jsub < 4; ++jsub) {
      const int js = s * 4 + jsub;
      const int jn = (js < 7) ? js + 1 : js;

      s16x8 bfn[4];
#pragma unroll
      for (int c = 0; c < 4; ++c)
        bfn[c] = *(const s16x8*)(Vb + jn * 2048 + c * 512);
      float4 T0 = ((const float4*)(sdh + jn * 32))[0];
      float4 T1 = ((const float4*)(sdh + jn * 32 + 4))[0];

      const unsigned wq0 = Wd0[jsub] >> shq;
      const unsigned wq1 = Wd1[jsub] >> shq;

#pragma unroll
      for (int rf = 0; rf < 2; ++rf) {
        const float src_i = rf ? src1 : src0;
        const unsigned wq = rf ? wq1 : wq0;
        float p[8];
#define PGEN(dv, e)                                                           \
        { float tp = src_i + (dv);                                            \
          float u  = fmaxf(tp, fmaf(tp, 0.2f, -800.0f));                      \
          u = fmaf((float)((wq >> (e)) & 1u), 1000.0f, u);                    \
          p[e] = hexp2(u); }
        PGEN(S0.x, 0) PGEN(S0.y, 1) PGEN(S0.z, 2) PGEN(S0.w, 3)
        PGEN(S1.x, 4) PGEN(S1.y, 5) PGEN(S1.z, 6) PGEN(S1.w, 7)
#undef PGEN
        union { int i4[4]; s16x8 v; } af;
        af.i4[0] = pkbf(p[0], p[1]);
        af.i4[1] = pkbf(p[2], p[3]);
        af.i4[2] = pkbf(p[4], p[5]);
        af.i4[3] = pkbf(p[6], p[7]);
#pragma unroll
        for (int c = 0; c < 4; ++c)
          acc[rf][c] = __builtin_amdgcn_mfma_f32_16x16x32_bf16(af.v, bfc[c], acc[rf][c], 0, 0, 0);
        accl[rf] = __builtin_amdgcn_mfma_f32_16x16x32_bf16(af.v, bones, accl[rf], 0, 0, 0);
      }
#pragma unroll
      for (int c = 0; c < 4; ++c) bfc[c] = bfn[c];
      S0 = T0; S1 = T1;
    }
#pragma unroll
    for (int e = 0; e < 4; ++e) { Wd0[e] = nWd0[e]; Wd1[e] = nWd1[e]; }
  }

  // ---- merge 8 j-chunks -> partial for this (rt, h, jh) ----
  if (lm == 0) {
#pragma unroll
    for (int rf = 0; rf < 2; ++rf)
#pragma unroll
      for (int g = 0; g < 4; ++g)
        Lm[w][rf * 16 + q * 4 + g] = accl[rf][g];
  }
  if (w >= 4) {
#pragma unroll
    for (int rf = 0; rf < 2; ++rf)
#pragma unroll
      for (int c = 0; c < 4; ++c)
#pragma unroll
        for (int g = 0; g < 4; ++g)
          MRG[w - 4][rf * 16 + q * 4 + g][c * 16 + lm] = acc[rf][c][g];
  }
  __syncthreads();
  if (w < 4) {
#pragma unroll
    for (int rf = 0; rf < 2; ++rf)
#pragma unroll
      for (int c = 0; c < 4; ++c)
#pragma unroll
        for (int g = 0; g < 4; ++g)
          acc[rf][c][g] += MRG[w][rf * 16 + q * 4 + g][c * 16 + lm];
  }
  __syncthreads();
  if (w >= 1 && w < 4) {
#pragma unroll
    for (int rf = 0; rf < 2; ++rf)
#pragma unroll
      for (int c = 0; c < 4; ++c)
#pragma unroll
        for (int g = 0; g < 4; ++g)
          MRG[w - 1][rf * 16 + q * 4 + g][c * 16 + lm] = acc[rf][c][g];
  }
  __syncthreads();
  if (w == 0) {
#pragma unroll
    for (int rf = 0; rf < 2; ++rf) {
#pragma unroll
      for (int g = 0; g < 4; ++g) {
        const int row = rf * 16 + q * 4 + g;
        if (lm == 0) {
          float l = 0.f;
#pragma unroll
          for (int ww = 0; ww < 8; ++ww) l += Lm[ww][row];
          Pl[(size_t)b * 32 + row] = l;
        }
#pragma unroll
        for (int c = 0; c < 4; ++c) {
          const int col = c * 16 + lm;
          float v = acc[rf][c][g]
                  + MRG[0][row][col] + MRG[1][row][col] + MRG[2][row][col];
          Pn[((size_t)b * 32 + row) * 64 + col] = v;
        }
      }
    }
  }
}

// ---------------------------------------------------------------------------
// Final combine: out = relu((Pn0+Pn1)/(Pl0+Pl1) + bias). 1 float4 per thread.
// ---------------------------------------------------------------------------
__global__ __launch_bounds__(256) void gat_fin(
    const float* __restrict__ Pn, const float* __restrict__ Pl,
    const float* __restrict__ bias, float* __restrict__ out)
{
  const int f = blockIdx.x * 256 + threadIdx.x;   // 0..262143
  const int row = f >> 6;
  const int c4  = f & 63;
  const int h   = c4 >> 4;
  const int cd  = (c4 & 15) * 4;
  const int rt  = row >> 5, r32 = row & 31;

  const int pb0 = ((rt * 4 + h) << 1);
  const size_t base0 = ((size_t)pb0 * 32 + r32) * 64 + cd;
  float4 n0 = *(const float4*)(Pn + base0);
  float4 n1 = *(const float4*)(Pn + base0 + 32 * 64);
  const float l = Pl[(size_t)pb0 * 32 + r32] + Pl[(size_t)(pb0 + 1) * 32 + r32];
  const float inv = 1.0f / l;
  float4 bv = *(const float4*)(bias + h * 64 + cd);
  float4 o;
  o.x = fmaxf(fmaf(n0.x + n1.x, inv, bv.x), 0.f);
  o.y = fmaxf(fmaf(n0.y + n1.y, inv, bv.y), 0.f);
  o.z = fmaxf(fmaf(n0.z + n1.z, inv, bv.z), 0.f);
  o.w = fmaxf(fmaf(n0.w + n1.w, inv, bv.w), 0.f);
  *(float4*)(out + (size_t)row * 256 + h * 64 + cd) = o;
}

// ---------------------------------------------------------------------------
extern "C" void kernel_launch(void* const* d_in, const int* in_sizes, int n_in,
                              void* d_out, int out_size, void* d_ws, size_t ws_size,
                              hipStream_t stream) {
  const float* x    = (const float*)d_in[0];
  const int*   adj  = (const int*)d_in[1];
  const float* W    = (const float*)d_in[2];
  const float* a    = (const float*)d_in[3];
  const float* bias = (const float*)d_in[4];
  float* out = (float*)d_out;

  // ws: V2 2MB | bits 2MB | ssrc 64KB | sdst 64KB | Pn 8MB | Pl 128KB
  short* V2 = (short*)d_ws;
  unsigned long long* bits =
      (unsigned long long*)((char*)d_ws + (size_t)2 * 1024 * 1024);
  float* ssrc = (float*)((char*)d_ws + (size_t)4 * 1024 * 1024);
  float* sdst = ssrc + NH * NN;
  float* Pn   = (float*)((char*)d_ws + (size_t)5 * 1024 * 1024);
  float* Pl   = (float*)((char*)d_ws + (size_t)13 * 1024 * 1024);

  gat_pre<<<768, 512, 0, stream>>>(adj, x, W, a, bits, V2, ssrc, sdst);
  gat_k2p<<<1024, 512, 0, stream>>>((const unsigned*)bits, V2, ssrc, sdst, Pn, Pl);
  gat_fin<<<1024, 256, 0, stream>>>(Pn, Pl, bias, out);
}